// Round 1
// baseline (192.468 us; speedup 1.0000x reference)
//
#include <hip/hip_runtime.h>

// Problem constants (from reference): N=256, V=4, L=100000.
// out[n][v][l] = mask[n][l] ? (cats[n][l] == v ? 1 : 0) : s[n][v][l]
//
// Memory-bound elementwise select. Each thread processes 4 consecutive l
// positions (int4/float4 vector accesses) for one n across all V=4 planes,
// so mask/cats are fetched exactly once.

#define N_SEQ 256
#define V_VOCAB 4
#define L_LEN 100000
#define L4 (L_LEN / 4)   // 25000, exact

__global__ void mutate_kernel(const float* __restrict__ s,
                              const int* __restrict__ mask,
                              const int* __restrict__ cats,
                              float* __restrict__ out) {
    const long long total = (long long)N_SEQ * L4;   // 6.4M vector-work items
    const long long stride = (long long)gridDim.x * blockDim.x;
    for (long long idx = (long long)blockIdx.x * blockDim.x + threadIdx.x;
         idx < total; idx += stride) {
        const int n  = (int)(idx / L4);
        const int lc = (int)(idx % L4);
        const long long nl = (long long)n * L_LEN + (long long)lc * 4;

        const int4 m = *reinterpret_cast<const int4*>(mask + nl);
        const int4 c = *reinterpret_cast<const int4*>(cats + nl);

        #pragma unroll
        for (int v = 0; v < V_VOCAB; ++v) {
            const long long off = ((long long)n * V_VOCAB + v) * L_LEN
                                + (long long)lc * 4;
            const float4 sv = *reinterpret_cast<const float4*>(s + off);
            float4 o;
            o.x = m.x ? (c.x == v ? 1.0f : 0.0f) : sv.x;
            o.y = m.y ? (c.y == v ? 1.0f : 0.0f) : sv.y;
            o.z = m.z ? (c.z == v ? 1.0f : 0.0f) : sv.z;
            o.w = m.w ? (c.w == v ? 1.0f : 0.0f) : sv.w;
            *reinterpret_cast<float4*>(out + off) = o;
        }
    }
}

extern "C" void kernel_launch(void* const* d_in, const int* in_sizes, int n_in,
                              void* d_out, int out_size, void* d_ws, size_t ws_size,
                              hipStream_t stream) {
    const float* s    = (const float*)d_in[0];   // (N, V, L) float32 one-hot
    const int*   mask = (const int*)d_in[1];     // (N, L) bool -> int32
    const int*   cats = (const int*)d_in[2];     // (N, L) int32
    float* out = (float*)d_out;                  // (N, V, L) float32

    const int block = 256;
    const long long total = (long long)N_SEQ * L4;
    int grid = (int)((total + block - 1) / block);
    if (grid > 2048) grid = 2048;   // grid-stride the rest (G11)

    mutate_kernel<<<grid, block, 0, stream>>>(s, mask, cats, out);
}